// Round 1
// baseline (485.189 us; speedup 1.0000x reference)
//
#include <hip/hip_runtime.h>
#include <hip/hip_bf16.h>
#include <cstdint>

typedef __attribute__((ext_vector_type(4))) float f32x4;
typedef __attribute__((ext_vector_type(8))) short bf16x8;
typedef unsigned short u16;

__device__ inline u16 f2b(float f) {
    union { float f; uint32_t u; } c; c.f = f;
    uint32_t r = (c.u + 0x7FFFu + ((c.u >> 16) & 1u)) >> 16;
    return (u16)r;
}

// ---- Kernel 1: cast X f32 -> bf16 bits (vectorized) ----
__global__ void cast_x_kernel(const float4* __restrict__ X, ushort4* __restrict__ Xb, int n4) {
    int i = blockIdx.x * blockDim.x + threadIdx.x;
    int stride = gridDim.x * blockDim.x;
    for (; i < n4; i += stride) {
        float4 v = X[i];
        ushort4 o;
        o.x = f2b(v.x); o.y = f2b(v.y); o.z = f2b(v.z); o.w = f2b(v.w);
        Xb[i] = o;
    }
}

// ---- Kernel 2: FWHT over each contiguous 1024-block of W rows, scale 1/32, emit bf16 ----
__global__ void fwht_w_kernel(const float* __restrict__ W, u16* __restrict__ Wh) {
    __shared__ float s[1024];
    const float* src = W + (size_t)blockIdx.x * 1024;
    for (int i = threadIdx.x; i < 1024; i += 256) s[i] = src[i];
    __syncthreads();
    for (int h = 1; h < 1024; h <<= 1) {
        for (int p = threadIdx.x; p < 512; p += 256) {
            int i = ((p & ~(h - 1)) << 1) | (p & (h - 1));
            float a = s[i], b = s[i + h];
            s[i] = a + b;
            s[i + h] = a - b;
        }
        __syncthreads();
    }
    u16* dst = Wh + (size_t)blockIdx.x * 1024;
    for (int i = threadIdx.x; i < 1024; i += 256) dst[i] = f2b(s[i] * 0.03125f);
}

// ---- Kernel 3: bf16 GEMM C = A * B^T (A: MxK, B: NxK, C: MxN f32) ----
// m97 structure: 128x128 tile, BK=32, 4 waves 2x2, 16x16x32 MFMA, global_load_lds(16B)
#define BM 128
#define BN 128
#define BK 32

__global__ __launch_bounds__(256) void gemm_bt_kernel(
    const u16* __restrict__ A,   // M x K bf16 bits
    const u16* __restrict__ B,   // N x K bf16 bits
    float* __restrict__ C,       // M x N f32
    int M, int N, int K)
{
    __shared__ u16 sA[BM * BK];
    __shared__ u16 sB[BN * BK];

    const int tid  = threadIdx.x;
    const int wid  = tid >> 6;
    const int lane = tid & 63;
    const int wr   = wid >> 1;   // wave row 0..1
    const int wc   = wid & 1;    // wave col 0..1

    // XCD-aware bijective swizzle (nwg % 8 == 0 here)
    const int ntn = N / BN;
    const int nwg = (M / BM) * ntn;
    int bid = blockIdx.x;
    int swz = (nwg % 8 == 0) ? ((bid & 7) * (nwg >> 3) + (bid >> 3)) : bid;
    const int tm = swz / ntn;
    const int tn = swz % ntn;

    const size_t rowA0 = (size_t)tm * BM;
    const size_t rowB0 = (size_t)tn * BN;

    f32x4 acc[4][4];
#pragma unroll
    for (int i = 0; i < 4; ++i)
#pragma unroll
        for (int j = 0; j < 4; ++j)
            acc[i][j] = (f32x4)(0.0f);

    const int lrow = lane >> 2;         // 0..15
    const int lcol = (lane & 3) * 8;    // 0,8,16,24

    for (int k0 = 0; k0 < K; k0 += BK) {
        // stage A and B tiles: per wave, chunk = contiguous 1KB (16 rows x 32 k)
#pragma unroll
        for (int i = 0; i < 2; ++i) {
            int chunk = i * 4 + wid;                 // 0..7
            int row   = chunk * 16 + lrow;
            const u16* gA = A + (rowA0 + row) * K + k0 + lcol;
            const u16* gB = B + (rowB0 + row) * K + k0 + lcol;
            u16* lA = sA + chunk * 512;              // wave-uniform LDS base
            u16* lB = sB + chunk * 512;
            __builtin_amdgcn_global_load_lds((const __attribute__((address_space(1))) void*)gA,
                                             (__attribute__((address_space(3))) void*)lA, 16, 0, 0);
            __builtin_amdgcn_global_load_lds((const __attribute__((address_space(1))) void*)gB,
                                             (__attribute__((address_space(3))) void*)lB, 16, 0, 0);
        }
        __syncthreads();

        bf16x8 af[4], bfr[4];
        const int kf   = (lane >> 4) * 8;
        const int rsel = lane & 15;
#pragma unroll
        for (int mf = 0; mf < 4; ++mf)
            af[mf] = *(const bf16x8*)&sA[(wr * 64 + mf * 16 + rsel) * BK + kf];
#pragma unroll
        for (int nf = 0; nf < 4; ++nf)
            bfr[nf] = *(const bf16x8*)&sB[(wc * 64 + nf * 16 + rsel) * BK + kf];

#pragma unroll
        for (int mf = 0; mf < 4; ++mf)
#pragma unroll
            for (int nf = 0; nf < 4; ++nf)
                acc[mf][nf] = __builtin_amdgcn_mfma_f32_16x16x32_bf16(af[mf], bfr[nf], acc[mf][nf], 0, 0, 0);
        __syncthreads();
    }

    // epilogue: C/D layout col = lane&15, row = (lane>>4)*4 + reg
#pragma unroll
    for (int mf = 0; mf < 4; ++mf) {
        int row = (int)rowA0 + wr * 64 + mf * 16 + (lane >> 4) * 4;
#pragma unroll
        for (int nf = 0; nf < 4; ++nf) {
            int col = (int)rowB0 + wc * 64 + nf * 16 + (lane & 15);
            f32x4 v = acc[mf][nf];
#pragma unroll
            for (int j = 0; j < 4; ++j)
                C[(size_t)(row + j) * N + col] = v[j];
        }
    }
}

extern "C" void kernel_launch(void* const* d_in, const int* in_sizes, int n_in,
                              void* d_out, int out_size, void* d_ws, size_t ws_size,
                              hipStream_t stream) {
    const float* X = (const float*)d_in[0];   // (4,2048,4096) f32
    const float* W = (const float*)d_in[1];   // (4096,4096) f32
    float* Out = (float*)d_out;               // (4,2048,4096) f32

    const int K = 4096;
    const int N = in_sizes[1] / K;            // 4096
    const int M = in_sizes[0] / K;            // 8192

    u16* Xb = (u16*)d_ws;                     // M*K bf16 (64 MB)
    u16* Wh = (u16*)d_ws + (size_t)M * K;     // N*K bf16 (32 MB)

    cast_x_kernel<<<2048, 256, 0, stream>>>((const float4*)X, (ushort4*)Xb, (M * K) / 4);
    fwht_w_kernel<<<(size_t)N * K / 1024, 256, 0, stream>>>(W, Wh);

    dim3 grid((M / BM) * (N / BN));
    gemm_bt_kernel<<<grid, 256, 0, stream>>>(Xb, Wh, Out, M, N, K);
}

// Round 2
// 316.593 us; speedup vs baseline: 1.5325x; 1.5325x over previous
//
#include <hip/hip_runtime.h>
#include <hip/hip_bf16.h>
#include <cstdint>

typedef __attribute__((ext_vector_type(4))) float f32x4;
typedef __attribute__((ext_vector_type(8))) short bf16x8;
typedef unsigned short u16;

__device__ inline u16 f2b(float f) {
    union { float f; uint32_t u; } c; c.f = f;
    uint32_t r = (c.u + 0x7FFFu + ((c.u >> 16) & 1u)) >> 16;
    return (u16)r;
}

// ---- Kernel 1: cast X f32 -> bf16 bits (vectorized) ----
__global__ void cast_x_kernel(const float4* __restrict__ X, ushort4* __restrict__ Xb, int n4) {
    int i = blockIdx.x * blockDim.x + threadIdx.x;
    int stride = gridDim.x * blockDim.x;
    for (; i < n4; i += stride) {
        float4 v = X[i];
        ushort4 o;
        o.x = f2b(v.x); o.y = f2b(v.y); o.z = f2b(v.z); o.w = f2b(v.w);
        Xb[i] = o;
    }
}

// ---- Kernel 2: FWHT over each contiguous 1024-block of W rows, scale 1/32, emit bf16 ----
__global__ void fwht_w_kernel(const float* __restrict__ W, u16* __restrict__ Wh) {
    __shared__ float s[1024];
    const float* src = W + (size_t)blockIdx.x * 1024;
    for (int i = threadIdx.x; i < 1024; i += 256) s[i] = src[i];
    __syncthreads();
    for (int h = 1; h < 1024; h <<= 1) {
        for (int p = threadIdx.x; p < 512; p += 256) {
            int i = ((p & ~(h - 1)) << 1) | (p & (h - 1));
            float a = s[i], b = s[i + h];
            s[i] = a + b;
            s[i + h] = a - b;
        }
        __syncthreads();
    }
    u16* dst = Wh + (size_t)blockIdx.x * 1024;
    for (int i = threadIdx.x; i < 1024; i += 256) dst[i] = f2b(s[i] * 0.03125f);
}

// ---- Kernel 3: 256x256-tile 8-wave 4-phase pipelined bf16 GEMM, C = A * B^T ----
// A: MxK bf16, B: NxK bf16, C: MxN f32.  BK=64.  LDS: 2buf x {A,B} x 2half x [128][64],
// 16B-slot XOR swizzle (slot ^= row&7) via pre-swizzled global source + swizzled read.
#define MFMA16(a, b, c) __builtin_amdgcn_mfma_f32_16x16x32_bf16(a, b, c, 0, 0, 0)

__global__ __launch_bounds__(512) void gemm256_kernel(
    const u16* __restrict__ A, const u16* __restrict__ B, float* __restrict__ C,
    int M, int N, int K)
{
    __shared__ u16 lds[2][2][2][8192];   // [buf][op A=0/B=1][half][128*64]

    const int tid  = threadIdx.x;
    const int wid  = tid >> 6;
    const int lane = tid & 63;
    const int wr   = wid >> 2;           // 0..1
    const int wc   = wid & 3;            // 0..3

    const int ntn = N / 256;
    const int nwg = (M / 256) * ntn;
    int bid = blockIdx.x;
    int swz = (nwg % 8 == 0) ? ((bid & 7) * (nwg >> 3) + (bid >> 3)) : bid;
    const int tm = swz / ntn, tn = swz % ntn;
    const size_t rowA0 = (size_t)tm * 256;
    const size_t rowB0 = (size_t)tn * 256;
    const int TSTEPS = K / 64;

    // staging constants: wave w covers rows chunk*64 + w*8 .. +8 of a half-tile
    const int stg_row  = wid * 8 + (lane >> 3);            // row within 64-row chunk block
    const int stg_slot = (lane & 7) ^ (stg_row & 7);       // pre-swizzled source 16B-slot

    // read-side constants (row within half r: r&7 == lane&7)
    const int frow = (lane & 15) * 64;                                  // u16 offset of row
    const int fs0  = (((lane >> 4)) ^ (lane & 7)) * 8;                  // ks=0 slot
    const int fs1  = ((4 + (lane >> 4)) ^ (lane & 7)) * 8;              // ks=1 slot

    auto stage = [&](const u16* __restrict__ G, size_t rowbase, u16* ldsHalf, int chunk, int t) {
        int teff = t < TSTEPS ? t : TSTEPS - 1;
        const u16* g = G + (rowbase + (size_t)(chunk * 64 + stg_row)) * (size_t)K
                         + teff * 64 + stg_slot * 8;
        u16* l = ldsHalf + chunk * 4096 + wid * 512;       // wave-uniform base; HW adds lane*16B
        __builtin_amdgcn_global_load_lds((const __attribute__((address_space(1))) void*)g,
                                         (__attribute__((address_space(3))) void*)l, 16, 0, 0);
    };

    f32x4 acc[8][4];
#pragma unroll
    for (int i = 0; i < 8; ++i)
#pragma unroll
        for (int j = 0; j < 4; ++j) acc[i][j] = (f32x4)(0.0f);

    bf16x8 aR[4][2], b0R[2][2], b1R[2][2];

    // ---- prologue: tile0 (4 half-tiles) + tile1's B0,A0,A1 (steady stream tail) ----
    stage(A, rowA0,       &lds[0][0][0][0], 0, 0);
    stage(A, rowA0,       &lds[0][0][0][0], 1, 0);
    stage(B, rowB0,       &lds[0][1][0][0], 0, 0);
    stage(B, rowB0,       &lds[0][1][0][0], 1, 0);
    stage(A, rowA0 + 128, &lds[0][0][1][0], 0, 0);
    stage(A, rowA0 + 128, &lds[0][0][1][0], 1, 0);
    stage(B, rowB0 + 128, &lds[0][1][1][0], 0, 0);
    stage(B, rowB0 + 128, &lds[0][1][1][0], 1, 0);
    stage(B, rowB0,       &lds[1][1][0][0], 0, 1);
    stage(B, rowB0,       &lds[1][1][0][0], 1, 1);
    stage(A, rowA0,       &lds[1][0][0][0], 0, 1);
    stage(A, rowA0,       &lds[1][0][0][0], 1, 1);
    stage(A, rowA0 + 128, &lds[1][0][1][0], 0, 1);
    stage(A, rowA0 + 128, &lds[1][0][1][0], 1, 1);
    asm volatile("s_waitcnt vmcnt(6)" ::: "memory");   // tile0 fully landed; 3 half-tiles in flight
    __builtin_amdgcn_s_barrier();

    for (int t = 0; t < TSTEPS; ++t) {
        const int cb = t & 1, nb = cb ^ 1;
        const u16* Ahalf = &lds[cb][0][wr][0];
        const u16* Bbase = &lds[cb][1][wc >> 1][(wc & 1) * 4096];

        // ===== phase 0: quadrant (mq0, nq0) =====
#pragma unroll
        for (int i = 0; i < 4; ++i) {
            aR[i][0] = *(const bf16x8*)&Ahalf[i * 1024 + frow + fs0];
            aR[i][1] = *(const bf16x8*)&Ahalf[i * 1024 + frow + fs1];
        }
#pragma unroll
        for (int j = 0; j < 2; ++j) {
            b0R[j][0] = *(const bf16x8*)&Bbase[j * 1024 + frow + fs0];
            b0R[j][1] = *(const bf16x8*)&Bbase[j * 1024 + frow + fs1];
        }
        stage(B, rowB0 + 128, &lds[nb][1][1][0], 0, t + 1);   // B1(t+1)
        stage(B, rowB0 + 128, &lds[nb][1][1][0], 1, t + 1);
        __builtin_amdgcn_s_barrier();
        asm volatile("s_waitcnt lgkmcnt(0)" ::: "memory");
        __builtin_amdgcn_s_setprio(1);
#pragma unroll
        for (int i = 0; i < 4; ++i)
#pragma unroll
            for (int j = 0; j < 2; ++j) {
                acc[i][j] = MFMA16(aR[i][0], b0R[j][0], acc[i][j]);
                acc[i][j] = MFMA16(aR[i][1], b0R[j][1], acc[i][j]);
            }
        __builtin_amdgcn_s_setprio(0);
        __builtin_amdgcn_s_barrier();

        // ===== phase 1: quadrant (mq0, nq1) =====
#pragma unroll
        for (int j = 0; j < 2; ++j) {
            b1R[j][0] = *(const bf16x8*)&Bbase[(2 + j) * 1024 + frow + fs0];
            b1R[j][1] = *(const bf16x8*)&Bbase[(2 + j) * 1024 + frow + fs1];
        }
        __builtin_amdgcn_s_barrier();
        asm volatile("s_waitcnt lgkmcnt(0)" ::: "memory");
        __builtin_amdgcn_s_setprio(1);
#pragma unroll
        for (int i = 0; i < 4; ++i)
#pragma unroll
            for (int j = 0; j < 2; ++j) {
                acc[i][2 + j] = MFMA16(aR[i][0], b1R[j][0], acc[i][2 + j]);
                acc[i][2 + j] = MFMA16(aR[i][1], b1R[j][1], acc[i][2 + j]);
            }
        __builtin_amdgcn_s_setprio(0);
        __builtin_amdgcn_s_barrier();

        // ===== phase 2: quadrant (mq1, nq1) =====
#pragma unroll
        for (int i = 0; i < 4; ++i) {
            aR[i][0] = *(const bf16x8*)&Ahalf[(4 + i) * 1024 + frow + fs0];
            aR[i][1] = *(const bf16x8*)&Ahalf[(4 + i) * 1024 + frow + fs1];
        }
        stage(B, rowB0, &lds[cb][1][0][0], 0, t + 2);         // B0(t+2) into dead slot
        stage(B, rowB0, &lds[cb][1][0][0], 1, t + 2);
        __builtin_amdgcn_s_barrier();
        asm volatile("s_waitcnt lgkmcnt(0)" ::: "memory");
        __builtin_amdgcn_s_setprio(1);
#pragma unroll
        for (int i = 0; i < 4; ++i)
#pragma unroll
            for (int j = 0; j < 2; ++j) {
                acc[4 + i][2 + j] = MFMA16(aR[i][0], b1R[j][0], acc[4 + i][2 + j]);
                acc[4 + i][2 + j] = MFMA16(aR[i][1], b1R[j][1], acc[4 + i][2 + j]);
            }
        __builtin_amdgcn_s_setprio(0);
        __builtin_amdgcn_s_barrier();

        // ===== phase 3: quadrant (mq1, nq0), stage A(t+2), counted vmcnt =====
        stage(A, rowA0,       &lds[cb][0][0][0], 0, t + 2);   // A0(t+2)
        stage(A, rowA0,       &lds[cb][0][0][0], 1, t + 2);
        stage(A, rowA0 + 128, &lds[cb][0][1][0], 0, t + 2);   // A1(t+2)
        stage(A, rowA0 + 128, &lds[cb][0][1][0], 1, t + 2);
        asm volatile("s_waitcnt vmcnt(6)" ::: "memory");      // tile t+1 landed; keep 3 in flight
        __builtin_amdgcn_s_barrier();
        __builtin_amdgcn_s_setprio(1);
#pragma unroll
        for (int i = 0; i < 4; ++i)
#pragma unroll
            for (int j = 0; j < 2; ++j) {
                acc[4 + i][j] = MFMA16(aR[i][0], b0R[j][0], acc[4 + i][j]);
                acc[4 + i][j] = MFMA16(aR[i][1], b0R[j][1], acc[4 + i][j]);
            }
        __builtin_amdgcn_s_setprio(0);
        __builtin_amdgcn_s_barrier();
    }

    // ---- epilogue: C/D layout col = lane&15, row = (lane>>4)*4 + reg ----
#pragma unroll
    for (int mf = 0; mf < 8; ++mf) {
        size_t row = rowA0 + wr * 128 + mf * 16 + (lane >> 4) * 4;
#pragma unroll
        for (int nf = 0; nf < 4; ++nf) {
            size_t col = rowB0 + wc * 64 + nf * 16 + (lane & 15);
            f32x4 v = acc[mf][nf];
#pragma unroll
            for (int j = 0; j < 4; ++j)
                C[(row + j) * (size_t)N + col] = v[j];
        }
    }
}

extern "C" void kernel_launch(void* const* d_in, const int* in_sizes, int n_in,
                              void* d_out, int out_size, void* d_ws, size_t ws_size,
                              hipStream_t stream) {
    const float* X = (const float*)d_in[0];   // (4,2048,4096) f32
    const float* W = (const float*)d_in[1];   // (4096,4096) f32
    float* Out = (float*)d_out;               // (4,2048,4096) f32

    const int K = 4096;
    const int N = in_sizes[1] / K;            // 4096
    const int M = in_sizes[0] / K;            // 8192

    u16* Xb = (u16*)d_ws;                     // M*K bf16 (64 MB)
    u16* Wh = (u16*)d_ws + (size_t)M * K;     // N*K bf16 (32 MB)

    cast_x_kernel<<<2048, 256, 0, stream>>>((const float4*)X, (ushort4*)Xb, (M * K) / 4);
    fwht_w_kernel<<<(size_t)N * K / 1024, 256, 0, stream>>>(W, Wh);

    dim3 grid((M / 256) * (N / 256));
    gemm256_kernel<<<grid, 512, 0, stream>>>(Xb, Wh, Out, M, N, K);
}